// Round 10
// baseline (144.953 us; speedup 1.0000x reference)
//
#include <hip/hip_runtime.h>

#define H96 96
#define W96 96
#define HW  9216          // 96*96
#define NC  256
#define NB  2
#define NHEADS 8
#define HD  32
#define SCALE 0.17677669529663687f   // 1/sqrt(32)

typedef __attribute__((ext_vector_type(8))) short short8v;    // 8 bf16 (4 VGPRs)
typedef __attribute__((ext_vector_type(4))) float f32x4;
typedef __attribute__((ext_vector_type(16))) float f32x16;

__device__ __forceinline__ ushort f2bf(float f) {
    unsigned u = __float_as_uint(f);
    u += 0x7FFFu + ((u >> 16) & 1u);          // round-to-nearest-even
    return (ushort)(u >> 16);
}
__device__ __forceinline__ float bf2f(ushort h) {
    return __uint_as_float(((unsigned)h) << 16);
}

// ---------------------------------------------------------------------------
// x [B][C][HW] fp32 -> xt [B][HW][C] bf16 (pixel-major) AND xbm (m-major bf16)
// ---------------------------------------------------------------------------
__global__ __launch_bounds__(256)
void x_to_bf16t(const float* __restrict__ x, ushort* __restrict__ xt,
                ushort* __restrict__ xbm)
{
    __shared__ float tile[32][33];
    const int t = threadIdx.x;
    const int hw0 = blockIdx.x * 32, c0 = blockIdx.y * 32, b = blockIdx.z;

    const int r = t >> 3, cc = (t & 7) * 4;
    const size_t gidx = ((size_t)b * NC + c0 + r) * HW + hw0 + cc;
    const float4 v = *(const float4*)(x + gidx);
    tile[r][cc + 0] = v.x; tile[r][cc + 1] = v.y; tile[r][cc + 2] = v.z; tile[r][cc + 3] = v.w;
    ushort4 ob;
    ob.x = f2bf(v.x); ob.y = f2bf(v.y); ob.z = f2bf(v.z); ob.w = f2bf(v.w);
    *(ushort4*)(xbm + gidx) = ob;
    __syncthreads();

    const int hwr = t >> 3, c4 = (t & 7) * 4;
    ushort4 o;
    o.x = f2bf(tile[c4 + 0][hwr]);
    o.y = f2bf(tile[c4 + 1][hwr]);
    o.z = f2bf(tile[c4 + 2][hwr]);
    o.w = f2bf(tile[c4 + 3][hwr]);
    *(ushort4*)(xt + ((size_t)b * HW + hw0 + hwr) * NC + c0 + c4) = o;
}

// ---------------------------------------------------------------------------
// Both weight conversions in one launch. q rows (first 65536 of w_qkv) are
// pre-scaled by SCALE*log2(e) so attn's softmax runs in exp2 domain.
// ---------------------------------------------------------------------------
__global__ __launch_bounds__(256)
void conv_w(const float* __restrict__ wq, const float* __restrict__ wo,
            ushort* __restrict__ oq, ushort* __restrict__ oo)
{
    const int bid = blockIdx.x;
    if (bid < 192) {
        const int i = (bid * 256 + threadIdx.x) * 4;
        const float s = (i < 65536) ? (SCALE * 1.4426950408889634f) : 1.0f;
        const float4 v = *(const float4*)(wq + i);
        ushort4 u;
        u.x = f2bf(v.x * s); u.y = f2bf(v.y * s); u.z = f2bf(v.z * s); u.w = f2bf(v.w * s);
        *(ushort4*)(oq + i) = u;
    } else {
        const int i = ((bid - 192) * 256 + threadIdx.x) * 4;
        const float4 v = *(const float4*)(wo + i);
        ushort4 u;
        u.x = f2bf(v.x); u.y = f2bf(v.y); u.z = f2bf(v.z); u.w = f2bf(v.w);
        *(ushort4*)(oo + i) = u;
    }
}

// ---------------------------------------------------------------------------
// MFMA GEMM: acc[m][hw] = sum_c A[m][c] * Bt[pixel][c]   (A,Bt bf16)
// 128x128 tile, BK=64, 4 waves (2x2). global_load_lds w=16, XOR-swizzled LDS.
// 1-D grid, XCD-chunked, m-tile fastest -> B-panel stays in the XCD's L2.
// ---------------------------------------------------------------------------
__device__ __forceinline__ void stage_tile(const ushort* __restrict__ g, ushort* lds,
                                           int w, int lane)
{
    const int lr  = lane >> 3;
    const int swz = ((lane & 7) ^ lr) * 8;
    #pragma unroll
    for (int ii = 0; ii < 4; ++ii) {
        const int rowbase = w * 32 + ii * 8;
        const ushort* src = g + (size_t)(rowbase + lr) * NC + swz;
        __builtin_amdgcn_global_load_lds((const __attribute__((address_space(1))) void*)src,
                                         (__attribute__((address_space(3))) void*)(lds + rowbase * 64),
                                         16, 0, 0);
    }
}

template<int EPI>
__global__ __launch_bounds__(256)
void gemm_mfma(const ushort* __restrict__ A, const ushort* __restrict__ Bt,
               void* __restrict__ Cout, const float* __restrict__ bias,
               const ushort* __restrict__ resb, int Mtot)
{
    __shared__ __align__(16) ushort smem[128 * 136];
    ushort* As = smem;
    ushort* Bs = smem + 128 * 64;

    const int t = threadIdx.x;
    const int lane = t & 63, w = t >> 6;
    const int wm = w >> 1, wn = w & 1;

    const int l = blockIdx.x;
    const int chunk = (EPI == 0) ? 108 : 36;
    const int mt    = (EPI == 0) ? 6 : 2;
    const int id2 = (l & 7) * chunk + (l >> 3);
    const int n_tile = id2 / mt;
    const int n0 = n_tile * 128;
    const int m0 = (id2 - n_tile * mt) * 128;

    const ushort* Ag = A + (size_t)m0 * NC;
    const ushort* Bg = Bt + (size_t)n0 * NC;

    f32x4 acc[4][4];
    #pragma unroll
    for (int i = 0; i < 4; ++i)
        #pragma unroll
        for (int j = 0; j < 4; ++j)
            acc[i][j] = (f32x4){0.f, 0.f, 0.f, 0.f};

    for (int k0 = 0; k0 < NC; k0 += 64) {
        stage_tile(Ag + k0, As, w, lane);
        stage_tile(Bg + k0, Bs, w, lane);
        __syncthreads();
        #pragma unroll
        for (int ks = 0; ks < 2; ++ks) {
            const int kc = (lane >> 4) + ks * 4;
            const int sw = (kc ^ (lane & 7)) * 8;
            short8v af[4], bf_[4];
            #pragma unroll
            for (int f = 0; f < 4; ++f) {
                af[f]  = *(const short8v*)(As + (wm * 64 + f * 16 + (lane & 15)) * 64 + sw);
                bf_[f] = *(const short8v*)(Bs + (wn * 64 + f * 16 + (lane & 15)) * 64 + sw);
            }
            #pragma unroll
            for (int fi = 0; fi < 4; ++fi)
                #pragma unroll
                for (int fj = 0; fj < 4; ++fj)
                    acc[fi][fj] = __builtin_amdgcn_mfma_f32_16x16x32_bf16(af[fi], bf_[fj], acc[fi][fj], 0, 0, 0);
        }
        __syncthreads();
    }

    const int b = n0 / HW;
    const int hw0 = n0 - b * HW;

    if constexpr (EPI == 0) {
        #pragma unroll
        for (int fi = 0; fi < 4; ++fi)
            #pragma unroll
            for (int fj = 0; fj < 4; ++fj) {
                const int hwl = wn * 64 + fj * 16 + (lane & 15);
                const int ml  = wm * 64 + fi * 16 + (lane >> 4) * 4;
                ushort4 v4;
                v4.x = f2bf(acc[fi][fj][0]);
                v4.y = f2bf(acc[fi][fj][1]);
                v4.z = f2bf(acc[fi][fj][2]);
                v4.w = f2bf(acc[fi][fj][3]);
                *(ushort4*)(smem + hwl * 136 + ml) = v4;
            }
        __syncthreads();
        ushort* C = (ushort*)Cout;
        #pragma unroll
        for (int it = 0; it < 8; ++it) {
            const int cid = it * 256 + t;
            const int hwl = cid >> 4, mc = (cid & 15) * 8;
            const uint4 v = *(const uint4*)(smem + hwl * 136 + mc);
            *(uint4*)(C + ((size_t)b * HW + hw0 + hwl) * (size_t)Mtot + m0 + mc) = v;
        }
    } else {
        float* C = (float*)Cout;
        const int ncol = hw0 + wn * 64 + (lane & 15);
        #pragma unroll
        for (int fi = 0; fi < 4; ++fi)
            #pragma unroll
            for (int r = 0; r < 4; ++r) {
                const int m = m0 + wm * 64 + fi * 16 + (lane >> 4) * 4 + r;
                const float bm = bias[m];
                const size_t base = ((size_t)b * NC + m) * HW + ncol;
                #pragma unroll
                for (int fj = 0; fj < 4; ++fj)
                    C[base + fj * 16] = acc[fi][fj][r] + bm + bf2f(resb[base + fj * 16]);
            }
    }
}

// ---------------------------------------------------------------------------
// Attention via MFMA. Block = 32 center px (2 rows x 16 cols), 256 threads,
// 4 waves x 8 px. Halo 4x18 = 72 px (2.25x centers). One 32x32x16 MFMA/px.
// khT/qhT transposed [ch][row] stride 74 (37 words, conflict-free); q/k staged
// as pixel-pairs packed into b32 writes. Hi-lane unused k-slots use literal-0
// fragment words (both sides) — no zero-row padding. Spurious pair rows masked
// on the q side (0*k = 0). Softmax in exp2 domain (q pre-scaled by SCALE*log2e).
// ---------------------------------------------------------------------------
__global__ __launch_bounds__(256)
void attn_mfma(const ushort* __restrict__ qkvp, ushort* __restrict__ att)
{
    __shared__ ushort khT[32 * 74];  // [ch][halo row 0..71; 72,73 unused]
    __shared__ ushort qhT[32 * 74];
    __shared__ ushort vh[72 * 40];   // [halo px][32 ch]
    __shared__ float  vs[32 * 32];   // [center px][32 m]

    const int t = threadIdx.x;
    const int sraw = blockIdx.x;                       // 0..287
    const int s = (sraw & 7) * 36 + (sraw >> 3);       // XCD-chunked (288=8*36)
    const int h = blockIdx.y;
    const int b = blockIdx.z;
    const int I0 = (s / 6) * 2;                        // center row pair
    const int j0 = (s - (s / 6) * 6) * 16;             // center col start

    const ushort* P = qkvp + (size_t)b * HW * 768;
    const int qo = h * HD, ko = NC + h * HD, vo = 2 * NC + h * HD;

    // ---- staging: 288 q/k pair-units + 288 vh units ----
    for (int z = t; z < 576; z += 256) {
        if (z < 288) {
            const int arr = z & 1, chunk = (z >> 1) & 3, pair = z >> 3;
            const int px0 = pair * 2;                  // pairs never straddle rows
            const int hy = px0 / 18, hx = px0 - hy * 18;
            const int gi = I0 - 1 + hy, gj = j0 - 1 + hx;
            const int off = (arr ? ko : qo) + chunk * 8;
            uint4 v0 = {0, 0, 0, 0}, v1 = {0, 0, 0, 0};
            if (gi >= 0 && gi < H96) {
                const ushort* pr = P + (size_t)gi * W96 * 768 + off;
                if (gj >= 0 && gj < W96) v0 = *(const uint4*)(pr + (size_t)gj * 768);
                if (gj + 1 < W96)        v1 = *(const uint4*)(pr + (size_t)(gj + 1) * 768);
            }
            ushort* dst = (arr ? khT : qhT) + (chunk * 8) * 74 + px0;
            const unsigned a0[4] = {v0.x, v0.y, v0.z, v0.w};
            const unsigned a1[4] = {v1.x, v1.y, v1.z, v1.w};
            #pragma unroll
            for (int i = 0; i < 4; ++i) {
                *(unsigned*)(dst + (2 * i) * 74)     = (a0[i] & 0xFFFFu) | (a1[i] << 16);
                *(unsigned*)(dst + (2 * i + 1) * 74) = (a0[i] >> 16) | (a1[i] & 0xFFFF0000u);
            }
        } else {
            const int u = z - 288;
            const int px = u >> 2, chunk = u & 3;
            const int hy = px / 18, hx = px - hy * 18;
            const int gi = I0 - 1 + hy, gj = j0 - 1 + hx;
            uint4 vv = {0, 0, 0, 0};
            if (gi >= 0 && gi < H96 && gj >= 0 && gj < W96)
                vv = *(const uint4*)(P + ((size_t)gi * W96 + gj) * 768 + vo + chunk * 8);
            *(uint4*)(vh + px * 40 + chunk * 8) = vv;
        }
    }
    __syncthreads();

    // ---- vsum (3x3 box sum of v) in f32: 32 px x 8 quad-units ----
    {
        const int px = t >> 3, q4 = (t & 7) * 4;
        const int r = px >> 4, c = px & 15;
        float a0 = 0.f, a1 = 0.f, a2 = 0.f, a3 = 0.f;
        #pragma unroll
        for (int dy = 0; dy < 3; ++dy)
            #pragma unroll
            for (int dx = 0; dx < 3; ++dx) {
                const ushort4 u4 = *(const ushort4*)(vh + ((r + dy) * 18 + c + dx) * 40 + q4);
                a0 += bf2f(u4.x); a1 += bf2f(u4.y); a2 += bf2f(u4.z); a3 += bf2f(u4.w);
            }
        *(float4*)(vs + px * 32 + q4) = (float4){a0, a1, a2, a3};
    }
    __syncthreads();

    const int lane = t & 63, w = t >> 6;
    const int hi = lane >> 5, ch = lane & 31;
    const int rw = w >> 1;                 // waves 0,1 -> row 0; 2,3 -> row 1
    const int cbase = (w & 1) * 8;
    const ushort* kb = khT + ch * 74 + hi * 36 + rw * 18;
    const ushort* qb = qhT + ch * 74 + hi * 36 + rw * 18;

    #pragma unroll
    for (int p = 0; p < 8; ++p) {
        const int c = cbase + p;

        unsigned kk0, kk1, kk2, kk3, qq0, qq1, qq2, qq3;
        if ((p & 1) == 0) {
            kk0 = *(const unsigned*)(kb + c);
            kk1 = *(const unsigned*)(kb + c + 2);
            qq0 = *(const unsigned*)(qb + c);
            qq1 = *(const unsigned*)(qb + c + 2) & 0x0000FFFFu;    // spur row c+3
            if (hi == 0) {
                kk2 = *(const unsigned*)(kb + c + 18);
                kk3 = *(const unsigned*)(kb + c + 20);
                qq2 = *(const unsigned*)(qb + c + 18);
                qq3 = *(const unsigned*)(qb + c + 20) & 0x0000FFFFu; // spur c+21
            } else { kk2 = kk3 = qq2 = qq3 = 0u; }
        } else {
            kk0 = *(const unsigned*)(kb + c - 1);
            kk1 = *(const unsigned*)(kb + c + 1);
            qq0 = *(const unsigned*)(qb + c - 1) & 0xFFFF0000u;    // spur row c-1
            qq1 = *(const unsigned*)(qb + c + 1);
            if (hi == 0) {
                kk2 = *(const unsigned*)(kb + c + 17);
                kk3 = *(const unsigned*)(kb + c + 19);
                qq2 = *(const unsigned*)(qb + c + 17) & 0xFFFF0000u; // spur c+17
                qq3 = *(const unsigned*)(qb + c + 19);
            } else { kk2 = kk3 = qq2 = qq3 = 0u; }
        }

        union { unsigned u[4]; short8v v; } A_, B_;
        A_.u[0] = kk0; A_.u[1] = kk1; A_.u[2] = kk2; A_.u[3] = kk3;
        B_.u[0] = qq0; B_.u[1] = qq1; B_.u[2] = qq2; B_.u[3] = qq3;

        f32x16 dm;
        #pragma unroll
        for (int r = 0; r < 16; ++r) dm[r] = 0.f;
        dm = __builtin_amdgcn_mfma_f32_32x32x16_bf16(A_.v, B_.v, dm, 0, 0, 0);

        const int pxc = rw * 16 + c;
        float vsv[16];
        #pragma unroll
        for (int g = 0; g < 4; ++g) {
            const float4 vv = *(const float4*)(vs + pxc * 32 + g * 8 + hi * 4);
            vsv[g * 4 + 0] = vv.x; vsv[g * 4 + 1] = vv.y;
            vsv[g * 4 + 2] = vv.z; vsv[g * 4 + 3] = vv.w;
        }

        float sum = 0.f, out = 0.f;
        #pragma unroll
        for (int r = 0; r < 16; ++r) {
            const float pe = __builtin_amdgcn_exp2f(dm[r]);
            sum += pe;
            out = fmaf(pe, vsv[r], out);
        }
        sum += __shfl_xor(sum, 32);
        out += __shfl_xor(out, 32);

        if (hi == 0) {
            const float inv = __builtin_amdgcn_rcpf(sum);
            att[((size_t)b * HW + (size_t)(I0 + rw) * W96 + j0 + c) * NC + h * HD + ch] =
                f2bf(out * inv);
        }
    }
}

// ---------------------------------------------------------------------------
extern "C" void kernel_launch(void* const* d_in, const int* in_sizes, int n_in,
                              void* d_out, int out_size, void* d_ws, size_t ws_size,
                              hipStream_t stream)
{
    (void)in_sizes; (void)n_in; (void)out_size; (void)ws_size;
    const float* x     = (const float*)d_in[0];
    const float* w_qkv = (const float*)d_in[1];
    const float* w_out = (const float*)d_in[2];
    const float* b_out = (const float*)d_in[3];
    float* out = (float*)d_out;

    ushort* qkvp = (ushort*)d_ws;                        // [B*HW][768] bf16 28.3 MB
    ushort* attb = qkvp + (size_t)NB * HW * 768;         // [B*HW][256] bf16  9.4 MB
    ushort* xt   = attb + (size_t)NB * HW * NC;          // [B*HW][256] bf16  9.4 MB
    ushort* wqb  = xt   + (size_t)NB * HW * NC;          // [768][256] bf16
    ushort* wob  = wqb  + 768 * NC;                      // [256][256] bf16
    ushort* xbm  = wob  + NC * NC;                       // [B][256][HW] bf16 9.4 MB

    x_to_bf16t<<<dim3(HW / 32, NC / 32, NB), 256, 0, stream>>>(x, xt, xbm);
    conv_w<<<dim3(256), 256, 0, stream>>>(w_qkv, w_out, wqb, wob);
    gemm_mfma<0><<<dim3(864), 256, 0, stream>>>(wqb, xt, qkvp, nullptr, nullptr, 768);
    attn_mfma<<<dim3(288, NHEADS, NB), 256, 0, stream>>>(qkvp, attb);
    gemm_mfma<1><<<dim3(288), 256, 0, stream>>>(wob, attb, out, b_out, xbm, 256);
}